// Round 17
// baseline (116.618 us; speedup 1.0000x reference)
//
#include <hip/hip_runtime.h>

#define NB 8
#define NN 4096
#define DNF 64
#define NEDGE 1048576
#define DM 64
#define FF 64

#define SPB2 16           // segments (nodes) per Pass-B block
#define NSEG 32768
#define SORTBLK2 256      // blocks in hist/sort passes
#define EPB2 4096         // edges per hist/sort block

using f32x4 = __attribute__((ext_vector_type(4))) float;
using f32x2 = __attribute__((ext_vector_type(2))) float;
using s16x8 = __attribute__((ext_vector_type(8))) short;

__device__ __forceinline__ unsigned short f2b(float f) {
    union { float f; unsigned u; } v; v.f = f;
    unsigned r = (v.u + 0x7fffu + ((v.u >> 16) & 1u)) >> 16;
    return (unsigned short)r;
}
__device__ __forceinline__ float uif(unsigned u) {
    union { unsigned u; float f; } v; v.u = u;
    return v.f;
}

// Pack W [K x Ncols] (f32 row-major) into MFMA B-fragment order (bf16)
__device__ __forceinline__ void pack_one(const float* __restrict__ W,
                                         unsigned short* __restrict__ out,
                                         int K, int Ncols, int idx) {
    int j = idx & 7;
    int lane = (idx >> 3) & 63;
    int frag = idx >> 9;
    int KS = K >> 5;
    int ks = frag % KS;
    int nt = frag / KS;
    int k = ks * 32 + ((lane >> 4) << 3) + j;
    int col = nt * 16 + (lane & 15);
    out[idx] = f2b(W[k * Ncols + col]);
}

__global__ void pack_all(const float* __restrict__ Wm1, const float* __restrict__ Wm2,
                         const float* __restrict__ Wu1, const float* __restrict__ Wu2,
                         unsigned short* __restrict__ Qw, unsigned short* __restrict__ Pw,
                         unsigned short* __restrict__ Wm2p,
                         unsigned short* __restrict__ Wu1p, unsigned short* __restrict__ Wu2p) {
    int idx = blockIdx.x * 256 + threadIdx.x;
    if (idx < 8192)        pack_one(Wm1,              Qw,   64, 128, idx);
    else if (idx < 16384)  pack_one(Wm1 + 64 * 128,   Pw,   64, 128, idx - 8192);
    else if (idx < 24576)  pack_one(Wm2,              Wm2p, 128, 64, idx - 16384);
    else if (idx < 40960)  pack_one(Wu1,              Wu1p, 128, 128, idx - 24576);
    else                   pack_one(Wu2,              Wu2p, 128, 64, idx - 40960);
}

__global__ void pack_weights(const float* __restrict__ W, unsigned short* __restrict__ out,
                             int K, int Ncols) {
    int idx = blockIdx.x * 256 + threadIdx.x;
    if (idx >= K * Ncols) return;
    pack_one(W, out, K, Ncols, idx);
}

// K1: blocks [0,256) = per-block 32768-bin segment histogram (u16 pairs packed
// in u32 LDS words, atomic 1<<(16*(seg&1))); blocks [256,512) = P = X@Wm1[64:].
__launch_bounds__(512, 4)
__global__ void hist_p(const int* __restrict__ eb, const int* __restrict__ esrc,
                       unsigned short* __restrict__ histm16,
                       const float* __restrict__ X,
                       const unsigned short* __restrict__ Pw,
                       unsigned short* __restrict__ Pp) {
    __shared__ unsigned lds_u[16384];   // 64 KB
    const int tid = threadIdx.x;
    if (blockIdx.x < SORTBLK2) {
        for (int i = tid; i < 16384; i += 512) lds_u[i] = 0;
        __syncthreads();
        const int e0 = blockIdx.x * EPB2;
#pragma unroll
        for (int i = 0; i < EPB2 / 512; ++i) {
            int e = e0 + i * 512 + tid;
            int seg = eb[e] * NN + esrc[e];
            atomicAdd(&lds_u[seg >> 1], 1u << ((seg & 1) * 16));
        }
        __syncthreads();
        unsigned* out32 = reinterpret_cast<unsigned*>(histm16) + (size_t)blockIdx.x * 16384;
        for (int i = tid; i < 16384; i += 512) out32[i] = lds_u[i];
    } else {
        unsigned short (*A)[72] = reinterpret_cast<unsigned short(*)[72]>(lds_u);
        const int g0 = (blockIdx.x - SORTBLK2) * 128;
        for (int i = 0; i < 16; ++i) {
            int idx = i * 512 + tid;
            int node = idx >> 6, f = idx & 63;
            A[node][f] = f2b(X[(size_t)(g0 + node) * DNF + f]);
        }
        __syncthreads();
        const int wave = tid >> 6, lane = tid & 63;
        const int lr = lane & 15, lq = lane >> 4;
        const int arow = wave * 16 + lr;
        s16x8 a[2];
#pragma unroll
        for (int ks = 0; ks < 2; ++ks)
            a[ks] = *reinterpret_cast<const s16x8*>(&A[arow][ks * 32 + lq * 8]);
#pragma unroll
        for (int nt = 0; nt < 8; ++nt) {
            f32x4 accP = {0.f, 0.f, 0.f, 0.f};
#pragma unroll
            for (int ks = 0; ks < 2; ++ks) {
                s16x8 bp = *reinterpret_cast<const s16x8*>(&Pw[(((nt << 1) + ks) * 64 + lane) * 8]);
                accP = __builtin_amdgcn_mfma_f32_16x16x32_bf16(a[ks], bp, accP, 0, 0, 0);
            }
            int col = nt * 16 + lr;
#pragma unroll
            for (int j = 0; j < 4; ++j) {
                int row = g0 + wave * 16 + lq * 4 + j;
                Pp[(size_t)row * 128 + col] = f2b(accP[j]);
            }
        }
    }
}

// K2a: column-wise exclusive prefix over histm16[256][32768] in place; totals out.
__launch_bounds__(256)
__global__ void scan_cols(unsigned short* __restrict__ histm16, unsigned* __restrict__ totals) {
    const int col = blockIdx.x * 256 + threadIdx.x;
    unsigned run = 0;
    for (int b = 0; b < SORTBLK2; ++b) {
        unsigned v = histm16[(size_t)b * NSEG + col];
        histm16[(size_t)b * NSEG + col] = (unsigned short)run;
        run += v;
    }
    totals[col] = run;
}

// K2b: exclusive scan of 32768 segment totals -> segBase[0..32768].
__launch_bounds__(1024)
__global__ void scan_tot(const unsigned* __restrict__ totals, unsigned* __restrict__ segBase) {
    __shared__ unsigned part[1024];
    const int t = threadIdx.x;
    unsigned v[32]; unsigned s = 0;
#pragma unroll
    for (int i = 0; i < 32; ++i) { v[i] = totals[t * 32 + i]; s += v[i]; }
    part[t] = s;
    __syncthreads();
    for (int off = 1; off < 1024; off <<= 1) {
        unsigned x = (t >= off) ? part[t - off] : 0u;
        __syncthreads();
        part[t] += x;
        __syncthreads();
    }
    unsigned run = t ? part[t - 1] : 0u;
#pragma unroll
    for (int i = 0; i < 32; ++i) { segBase[t * 32 + i] = run; run += v[i]; }
    if (t == 1023) segBase[NSEG] = run;
}

// K3: deterministic segment-sorted scatter. pos = segBase[seg] + histm[blk][seg]
// + local (packed-u16 LDS cursor). Fire-and-forget stores, zero global atomics.
// payload = dst[0:12) | w13[12:25)
__launch_bounds__(512, 4)
__global__ void sort_scatter(const int* __restrict__ eb, const int* __restrict__ esrc,
                             const int* __restrict__ edst, const float* __restrict__ evals,
                             const unsigned short* __restrict__ histm16,
                             const unsigned* __restrict__ segBase,
                             unsigned* __restrict__ payslot) {
    __shared__ unsigned curP[16384];    // 64 KB packed u16 cursors
    const int tid = threadIdx.x, blk = blockIdx.x;
    for (int i = tid; i < 16384; i += 512) curP[i] = 0;
    __syncthreads();
    const unsigned short* hrow = histm16 + (size_t)blk * NSEG;
    const int e0 = blk * EPB2;
#pragma unroll
    for (int i = 0; i < EPB2 / 512; ++i) {
        int e = e0 + i * 512 + tid;
        int seg = eb[e] * NN + esrc[e];
        unsigned wq = (unsigned)fminf(evals[e] * 8192.0f + 0.5f, 8191.0f);
        unsigned pay = (unsigned)edst[e] | (wq << 12);
        unsigned sh = (unsigned)(seg & 1) * 16u;
        unsigned old = atomicAdd(&curP[seg >> 1], 1u << sh);
        unsigned l = (old >> sh) & 0xffffu;
        payslot[segBase[seg] + (unsigned)hrow[seg] + l] = pay;
    }
}

// Pass B: 16 nodes per block. Payload is globally segment-sorted & dense:
// no staging, no LDS sort. Q computed in-block via MFMA (Qp buffer eliminated).
// Reduce streams each segment's run from L2 (wave-uniform broadcast loads).
__launch_bounds__(256, 8)
__global__ void bucket16_fused(const unsigned short* __restrict__ Pp,
                               const unsigned* __restrict__ payslot,
                               const unsigned* __restrict__ segBase,
                               const unsigned short* __restrict__ Qw,
                               const float* __restrict__ b1,
                               const unsigned short* __restrict__ Wm2p,
                               const float* __restrict__ b2m,
                               const float* __restrict__ X,
                               const unsigned short* __restrict__ Wu1p,
                               const float* __restrict__ bu1,
                               const unsigned short* __restrict__ Wu2p,
                               const float* __restrict__ bu2,
                               float* __restrict__ out) {
    __shared__ unsigned short A1[16][136];
    __shared__ unsigned short Qs[16][136];
    __shared__ unsigned short S[16][136];
    __shared__ unsigned short Hs[16][136];
    __shared__ float SW[16], SC[16];
    const int tid = threadIdx.x, wv = tid >> 6, lane = tid & 63;
    // XCD-affine swizzle: blocks round-robin XCDs; give XCD x the buckets of batch x.
    const int bkt = (blockIdx.x & 7) * 256 + (blockIdx.x >> 3);
    const int node0 = bkt * SPB2;
    const int rowbase = (bkt >> 8) << 12;         // batch * NN
    const int lr = lane & 15, lq = lane >> 4;

    // stage node feats into A1[:, 0:64]
#pragma unroll
    for (int i = 0; i < 4; ++i) {
        int idx = i * 256 + tid;
        int row = idx >> 6, f = idx & 63;
        A1[row][f] = f2b(X[(size_t)(node0 + row) * DNF + f]);
    }
    __syncthreads();

    // Q in-block: Qs[16][128] = X_tile @ Wm1[:64] + b1 (bias folded)
    {
        s16x8 a[2];
#pragma unroll
        for (int ks = 0; ks < 2; ++ks)
            a[ks] = *reinterpret_cast<const s16x8*>(&A1[lr][ks * 32 + lq * 8]);
#pragma unroll
        for (int t = 0; t < 2; ++t) {
            int nt = wv * 2 + t;
            f32x4 acc = {0.f, 0.f, 0.f, 0.f};
#pragma unroll
            for (int ks = 0; ks < 2; ++ks) {
                s16x8 bq = *reinterpret_cast<const s16x8*>(&Qw[(((nt << 1) + ks) * 64 + lane) * 8]);
                acc = __builtin_amdgcn_mfma_f32_16x16x32_bf16(a[ks], bq, acc, 0, 0, 0);
            }
            int col = nt * 16 + lr;
            float bias = b1[col];
#pragma unroll
            for (int j = 0; j < 4; ++j)
                Qs[lq * 4 + j][col] = f2b(acc[j] + bias);
        }
    }
    __syncthreads();

    const unsigned* P32 = reinterpret_cast<const unsigned*>(Pp);
    const unsigned* PbS = P32 + (size_t)rowbase * 64;
    for (int si = 0; si < 4; ++si) {
        const int lo = wv * 4 + si;
        const int seg = node0 + lo;
        const unsigned s0 = segBase[seg], s1 = segBase[seg + 1];
        unsigned qv = *reinterpret_cast<const unsigned*>(&Qs[lo][2 * lane]);
        f32x2 q2 = { uif(qv << 16), uif(qv & 0xffff0000u) };
        f32x2 acc2 = { 0.f, 0.f };
        float wsum = 0.f;

        for (unsigned bse = s0; bse < s1; bse += 8) {
            unsigned pv[8]; float wf[8];
#pragma unroll
            for (int k = 0; k < 8; ++k) {
                unsigned idx = bse + (unsigned)k;
                unsigned cu = (idx < s1) ? payslot[idx] : 0u;   // wave-uniform broadcast
                int ci = __builtin_amdgcn_readfirstlane((int)cu);
                wf[k] = (float)(unsigned)((ci >> 12) & 8191);   // integer-valued weight
                int row = ci & 0xfff;
                pv[k] = PbS[(size_t)row * 64 + lane];           // SADDR-form load
            }
#pragma unroll
            for (int k = 0; k < 8; ++k) {
                f32x2 p2 = { uif(pv[k] << 16), uif(pv[k] & 0xffff0000u) };
                f32x2 h2 = q2 + p2;
                h2 = __builtin_elementwise_max(h2, (f32x2){0.f, 0.f});
                acc2 += wf[k] * h2;
                wsum += wf[k];                                  // wave-uniform
            }
        }
        unsigned sp = (unsigned)f2b(acc2.x) | ((unsigned)f2b(acc2.y) << 16);
        *reinterpret_cast<unsigned*>(&S[lo][2 * lane]) = sp;
        if (lane == 0) {
            SW[lo] = wsum;
            SC[lo] = (1.0f / 8192.0f) / (float)max(s1 - s0, 1u);
        }
    }
    __syncthreads();

    // gathered = (S @ Wm2 + sumw*b2) * SC -> A1[:, 64:128] (bf16)
    {
        s16x8 a[4];
#pragma unroll
        for (int ks = 0; ks < 4; ++ks)
            a[ks] = *reinterpret_cast<const s16x8*>(&S[lr][ks * 32 + lq * 8]);
        f32x4 acc = {0.f, 0.f, 0.f, 0.f};
#pragma unroll
        for (int ks = 0; ks < 4; ++ks) {
            s16x8 bf = *reinterpret_cast<const s16x8*>(&Wm2p[(((wv << 2) + ks) * 64 + lane) * 8]);
            acc = __builtin_amdgcn_mfma_f32_16x16x32_bf16(a[ks], bf, acc, 0, 0, 0);
        }
        float bb = b2m[wv * 16 + lr];
#pragma unroll
        for (int j = 0; j < 4; ++j) {
            int r = lq * 4 + j;
            float g = (acc[j] + SW[r] * bb) * SC[r];
            A1[r][64 + wv * 16 + lr] = f2b(g);
        }
    }
    __syncthreads();

    // node MLP layer 1: relu([X|gathered] @ Wu1 + bu1) -> Hs
    {
        s16x8 a1[4];
#pragma unroll
        for (int ks = 0; ks < 4; ++ks)
            a1[ks] = *reinterpret_cast<const s16x8*>(&A1[lr][ks * 32 + lq * 8]);
#pragma unroll
        for (int t = 0; t < 2; ++t) {
            int nt = wv * 2 + t;
            f32x4 acc = {0.f, 0.f, 0.f, 0.f};
#pragma unroll
            for (int ks = 0; ks < 4; ++ks) {
                s16x8 bf = *reinterpret_cast<const s16x8*>(&Wu1p[(((nt << 2) + ks) * 64 + lane) * 8]);
                acc = __builtin_amdgcn_mfma_f32_16x16x32_bf16(a1[ks], bf, acc, 0, 0, 0);
            }
            float bias = bu1[nt * 16 + lr];
#pragma unroll
            for (int j = 0; j < 4; ++j) {
                float hh = fmaxf(acc[j] + bias, 0.f);
                Hs[lq * 4 + j][nt * 16 + lr] = f2b(hh);
            }
        }
    }
    __syncthreads();

    // layer 2: Hs @ Wu2 + bu2 -> out
    {
        s16x8 a2[4];
#pragma unroll
        for (int ks = 0; ks < 4; ++ks)
            a2[ks] = *reinterpret_cast<const s16x8*>(&Hs[lr][ks * 32 + lq * 8]);
        f32x4 acc = {0.f, 0.f, 0.f, 0.f};
#pragma unroll
        for (int ks = 0; ks < 4; ++ks) {
            s16x8 bf = *reinterpret_cast<const s16x8*>(&Wu2p[(((wv << 2) + ks) * 64 + lane) * 8]);
            acc = __builtin_amdgcn_mfma_f32_16x16x32_bf16(a2[ks], bf, acc, 0, 0, 0);
        }
        float bias = bu2[wv * 16 + lr];
#pragma unroll
        for (int j = 0; j < 4; ++j)
            out[(size_t)(node0 + lq * 4 + j) * FF + wv * 16 + lr] = acc[j] + bias;
    }
}

// ---------------- legacy fallback (small ws) ----------------

template<int SCALE>
__launch_bounds__(256, 4)
__global__ void node_kernel(const float* __restrict__ node_feats,
                            const float* __restrict__ sums, const float* __restrict__ counts,
                            const unsigned short* __restrict__ W1p, const float* __restrict__ b1,
                            const unsigned short* __restrict__ W2p, const float* __restrict__ b2,
                            float* __restrict__ out) {
    __shared__ unsigned short A1[64][136];
    __shared__ unsigned short Hs[64][136];
    const int tid = threadIdx.x;
    const int g0 = blockIdx.x * 64;
    for (int i = 0; i < 16; ++i) {
        int idx = i * 256 + tid;
        int node = idx >> 6;
        int p = idx & 63;
        int g = g0 + node;
        float2 v;
        if (p < 32) {
            v = *reinterpret_cast<const float2*>(node_feats + (size_t)g * DNF + 2 * p);
        } else {
            float2 s = *reinterpret_cast<const float2*>(sums + (size_t)g * DM + 2 * p - 64);
            if (SCALE) {
                float scale = 1.0f / fmaxf(counts[g], 1.0f);
                s.x *= scale; s.y *= scale;
            }
            v = s;
        }
        unsigned packed = (unsigned)f2b(v.x) | ((unsigned)f2b(v.y) << 16);
        *reinterpret_cast<unsigned*>(&A1[node][2 * p]) = packed;
    }
    __syncthreads();
    const int wave = tid >> 6, lane = tid & 63;
    const int lr = lane & 15, lq = lane >> 4;
    const int arow = wave * 16 + lr;
    s16x8 a[4];
#pragma unroll
    for (int ks = 0; ks < 4; ++ks)
        a[ks] = *reinterpret_cast<const s16x8*>(&A1[arow][ks * 32 + lq * 8]);
#pragma unroll
    for (int nt = 0; nt < 8; ++nt) {
        f32x4 acc = {0.f, 0.f, 0.f, 0.f};
#pragma unroll
        for (int ks = 0; ks < 4; ++ks) {
            s16x8 bf = *reinterpret_cast<const s16x8*>(&W1p[(((nt << 2) + ks) * 64 + lane) * 8]);
            acc = __builtin_amdgcn_mfma_f32_16x16x32_bf16(a[ks], bf, acc, 0, 0, 0);
        }
        float bias = b1[nt * 16 + lr];
#pragma unroll
        for (int j = 0; j < 4; ++j) {
            float h = acc[j] + bias;
            h = h > 0.f ? h : 0.f;
            Hs[wave * 16 + lq * 4 + j][nt * 16 + lr] = f2b(h);
        }
    }
    s16x8 a2[4];
#pragma unroll
    for (int ks = 0; ks < 4; ++ks)
        a2[ks] = *reinterpret_cast<const s16x8*>(&Hs[arow][ks * 32 + lq * 8]);
#pragma unroll
    for (int nt = 0; nt < 4; ++nt) {
        f32x4 acc = {0.f, 0.f, 0.f, 0.f};
#pragma unroll
        for (int ks = 0; ks < 4; ++ks) {
            s16x8 bf = *reinterpret_cast<const s16x8*>(&W2p[(((nt << 2) + ks) * 64 + lane) * 8]);
            acc = __builtin_amdgcn_mfma_f32_16x16x32_bf16(a2[ks], bf, acc, 0, 0, 0);
        }
        float bias = b2[nt * 16 + lr];
#pragma unroll
        for (int j = 0; j < 4; ++j) {
            int g = g0 + wave * 16 + lq * 4 + j;
            out[(size_t)g * FF + nt * 16 + lr] = acc[j] + bias;
        }
    }
}

__launch_bounds__(256, 4)
__global__ void edge_kernel(const float* __restrict__ node_feats,
                            const int* __restrict__ eb, const int* __restrict__ esrc,
                            const int* __restrict__ edst, const float* __restrict__ evals,
                            const unsigned short* __restrict__ W1p, const float* __restrict__ b1,
                            const unsigned short* __restrict__ W2p, const float* __restrict__ b2,
                            float* __restrict__ sums, float* __restrict__ counts) {
    __shared__ unsigned short A1[64][136];
    __shared__ unsigned short Hs[64][136];
    const int tid = threadIdx.x;
    const int e0 = blockIdx.x * 64;
    if (tid < 64) {
        int e = e0 + tid;
        atomicAdd(&counts[eb[e] * NN + esrc[e]], 1.0f);
    }
    for (int i = 0; i < 16; ++i) {
        int idx = i * 256 + tid;
        int edge = idx >> 6;
        int p = idx & 63;
        int e = e0 + edge;
        int b = eb[e];
        const float* row;
        if (p < 32) row = node_feats + ((size_t)b * NN + esrc[e]) * DNF;
        else        row = node_feats + ((size_t)b * NN + edst[e]) * DNF - 64;
        float2 v = *reinterpret_cast<const float2*>(row + 2 * p);
        unsigned packed = (unsigned)f2b(v.x) | ((unsigned)f2b(v.y) << 16);
        *reinterpret_cast<unsigned*>(&A1[edge][2 * p]) = packed;
    }
    __syncthreads();
    const int wave = tid >> 6, lane = tid & 63;
    const int lr = lane & 15, lq = lane >> 4;
    const int arow = wave * 16 + lr;
    s16x8 a[4];
#pragma unroll
    for (int ks = 0; ks < 4; ++ks)
        a[ks] = *reinterpret_cast<const s16x8*>(&A1[arow][ks * 32 + lq * 8]);
#pragma unroll
    for (int nt = 0; nt < 8; ++nt) {
        f32x4 acc = {0.f, 0.f, 0.f, 0.f};
#pragma unroll
        for (int ks = 0; ks < 4; ++ks) {
            s16x8 bf = *reinterpret_cast<const s16x8*>(&W1p[(((nt << 2) + ks) * 64 + lane) * 8]);
            acc = __builtin_amdgcn_mfma_f32_16x16x32_bf16(a[ks], bf, acc, 0, 0, 0);
        }
        float bias = b1[nt * 16 + lr];
#pragma unroll
        for (int j = 0; j < 4; ++j) {
            float h = acc[j] + bias;
            h = h > 0.f ? h : 0.f;
            Hs[wave * 16 + lq * 4 + j][nt * 16 + lr] = f2b(h);
        }
    }
    s16x8 a2[4];
#pragma unroll
    for (int ks = 0; ks < 4; ++ks)
        a2[ks] = *reinterpret_cast<const s16x8*>(&Hs[arow][ks * 32 + lq * 8]);
    float ev[4]; int seg4[4];
#pragma unroll
    for (int j = 0; j < 4; ++j) {
        int r = e0 + wave * 16 + lq * 4 + j;
        ev[j] = evals[r];
        seg4[j] = eb[r] * NN + esrc[r];
    }
#pragma unroll
    for (int nt = 0; nt < 4; ++nt) {
        f32x4 acc = {0.f, 0.f, 0.f, 0.f};
#pragma unroll
        for (int ks = 0; ks < 4; ++ks) {
            s16x8 bf = *reinterpret_cast<const s16x8*>(&W2p[(((nt << 2) + ks) * 64 + lane) * 8]);
            acc = __builtin_amdgcn_mfma_f32_16x16x32_bf16(a2[ks], bf, acc, 0, 0, 0);
        }
        float bias = b2[nt * 16 + lr];
#pragma unroll
        for (int j = 0; j < 4; ++j) {
            float m = (acc[j] + bias) * ev[j];
            atomicAdd(&sums[(size_t)seg4[j] * DM + nt * 16 + lr], m);
        }
    }
}

extern "C" void kernel_launch(void* const* d_in, const int* in_sizes, int n_in,
                              void* d_out, int out_size, void* d_ws, size_t ws_size,
                              hipStream_t stream) {
    const float* node_feats = (const float*)d_in[0];
    const int*   eb    = (const int*)d_in[1];
    const int*   esrc  = (const int*)d_in[2];
    const int*   edst  = (const int*)d_in[3];
    const float* evals = (const float*)d_in[4];
    const float* Wm1 = (const float*)d_in[5];
    const float* bm1 = (const float*)d_in[6];
    const float* Wm2 = (const float*)d_in[7];
    const float* bm2 = (const float*)d_in[8];
    const float* Wu1 = (const float*)d_in[9];
    const float* bu1 = (const float*)d_in[10];
    const float* Wu2 = (const float*)d_in[11];
    const float* bu2 = (const float*)d_in[12];
    float* out = (float*)d_out;
    char* ws = (char*)d_ws;

    const size_t NEED = 29720704;   // proven available (R9/R10 ran this branch)
    if (ws_size >= NEED) {
        unsigned short* Pp      = (unsigned short*)(ws);              // 8 MB
        unsigned*       payslot = (unsigned*)(ws + 8388608);          // 4 MB
        unsigned short* histm16 = (unsigned short*)(ws + 12582912);   // 256*32768*2 = 16 MB
        unsigned*       segBase = (unsigned*)(ws + 29360128);         // 32769*4 (pad 131200)
        unsigned*       totals  = (unsigned*)(ws + 29491328);         // 128 KB
        unsigned short* Qw      = (unsigned short*)(ws + 29622400);   // 16 KB
        unsigned short* Pw      = (unsigned short*)(ws + 29638784);   // 16 KB
        unsigned short* Wu1p    = (unsigned short*)(ws + 29655168);   // 32 KB
        unsigned short* Wu2p    = (unsigned short*)(ws + 29687936);   // 16 KB
        unsigned short* Wm2p    = (unsigned short*)(ws + 29704320);   // 16 KB

        pack_all<<<192, 256, 0, stream>>>(Wm1, Wm2, Wu1, Wu2, Qw, Pw, Wm2p, Wu1p, Wu2p);
        hist_p<<<2 * SORTBLK2, 512, 0, stream>>>(eb, esrc, histm16, node_feats, Pw, Pp);
        scan_cols<<<NSEG / 256, 256, 0, stream>>>(histm16, totals);
        scan_tot<<<1, 1024, 0, stream>>>(totals, segBase);
        sort_scatter<<<SORTBLK2, 512, 0, stream>>>(eb, esrc, edst, evals,
                                                   histm16, segBase, payslot);
        bucket16_fused<<<NSEG / SPB2, 256, 0, stream>>>(Pp, payslot, segBase,
                                                        Qw, bm1, Wm2p, bm2, node_feats,
                                                        Wu1p, bu1, Wu2p, bu2, out);
    } else {
        float* counts          = (float*)ws;
        unsigned short* W1p    = (unsigned short*)(ws + 131072);
        unsigned short* W2p    = (unsigned short*)(ws + 163840);
        unsigned short* Wu1p   = (unsigned short*)(ws + 180224);
        unsigned short* Wu2p   = (unsigned short*)(ws + 212992);
        hipMemsetAsync(d_out, 0, (size_t)out_size * sizeof(float), stream);
        hipMemsetAsync(counts, 0, 32768 * sizeof(float), stream);
        pack_weights<<<64, 256, 0, stream>>>(Wm1, W1p, 128, 128);
        pack_weights<<<32, 256, 0, stream>>>(Wm2, W2p, 128, 64);
        pack_weights<<<64, 256, 0, stream>>>(Wu1, Wu1p, 128, 128);
        pack_weights<<<32, 256, 0, stream>>>(Wu2, Wu2p, 128, 64);
        edge_kernel<<<NEDGE / 64, 256, 0, stream>>>(node_feats, eb, esrc, edst, evals,
                                                    W1p, bm1, W2p, bm2, out, counts);
        node_kernel<1><<<(NB * NN) / 64, 256, 0, stream>>>(node_feats, out, counts,
                                                           Wu1p, bu1, Wu2p, bu2, out);
    }
}

// Round 18
// 106.196 us; speedup vs baseline: 1.0981x; 1.0981x over previous
//
#include <hip/hip_runtime.h>

#define NB 8
#define NN 4096
#define DNF 64
#define NEDGE 1048576
#define DM 64
#define FF 64

#define SPB2 16           // segments (nodes) per Pass-B block
#define NSEG 32768
#define SORTBLK2 256      // blocks in hist/sort passes
#define EPB2 4096         // edges per hist/sort block
#define PCHUNK 1024       // Pass-B LDS payload chunk

using f32x4 = __attribute__((ext_vector_type(4))) float;
using f32x2 = __attribute__((ext_vector_type(2))) float;
using s16x8 = __attribute__((ext_vector_type(8))) short;

__device__ __forceinline__ unsigned short f2b(float f) {
    union { float f; unsigned u; } v; v.f = f;
    unsigned r = (v.u + 0x7fffu + ((v.u >> 16) & 1u)) >> 16;
    return (unsigned short)r;
}
__device__ __forceinline__ float uif(unsigned u) {
    union { unsigned u; float f; } v; v.u = u;
    return v.f;
}

// Pack W [K x Ncols] (f32 row-major) into MFMA B-fragment order (bf16)
__device__ __forceinline__ void pack_one(const float* __restrict__ W,
                                         unsigned short* __restrict__ out,
                                         int K, int Ncols, int idx) {
    int j = idx & 7;
    int lane = (idx >> 3) & 63;
    int frag = idx >> 9;
    int KS = K >> 5;
    int ks = frag % KS;
    int nt = frag / KS;
    int k = ks * 32 + ((lane >> 4) << 3) + j;
    int col = nt * 16 + (lane & 15);
    out[idx] = f2b(W[k * Ncols + col]);
}

__global__ void pack_all(const float* __restrict__ Wm1, const float* __restrict__ Wm2,
                         const float* __restrict__ Wu1, const float* __restrict__ Wu2,
                         unsigned short* __restrict__ Qw, unsigned short* __restrict__ Pw,
                         unsigned short* __restrict__ Wm2p,
                         unsigned short* __restrict__ Wu1p, unsigned short* __restrict__ Wu2p) {
    int idx = blockIdx.x * 256 + threadIdx.x;
    if (idx < 8192)        pack_one(Wm1,              Qw,   64, 128, idx);
    else if (idx < 16384)  pack_one(Wm1 + 64 * 128,   Pw,   64, 128, idx - 8192);
    else if (idx < 24576)  pack_one(Wm2,              Wm2p, 128, 64, idx - 16384);
    else if (idx < 40960)  pack_one(Wu1,              Wu1p, 128, 128, idx - 24576);
    else                   pack_one(Wu2,              Wu2p, 128, 64, idx - 40960);
}

__global__ void pack_weights(const float* __restrict__ W, unsigned short* __restrict__ out,
                             int K, int Ncols) {
    int idx = blockIdx.x * 256 + threadIdx.x;
    if (idx >= K * Ncols) return;
    pack_one(W, out, K, Ncols, idx);
}

// K1: blocks [0,256) = per-block 32768-bin segment histogram (u16 pairs packed
// in u32 LDS words); blocks [256,512) = P = X@Wm1[64:].
__launch_bounds__(512, 4)
__global__ void hist_p(const int* __restrict__ eb, const int* __restrict__ esrc,
                       unsigned short* __restrict__ histm16,
                       const float* __restrict__ X,
                       const unsigned short* __restrict__ Pw,
                       unsigned short* __restrict__ Pp) {
    __shared__ unsigned lds_u[16384];   // 64 KB
    const int tid = threadIdx.x;
    if (blockIdx.x < SORTBLK2) {
        for (int i = tid; i < 16384; i += 512) lds_u[i] = 0;
        __syncthreads();
        const int e0 = blockIdx.x * EPB2;
#pragma unroll
        for (int i = 0; i < EPB2 / 512; ++i) {
            int e = e0 + i * 512 + tid;
            int seg = eb[e] * NN + esrc[e];
            atomicAdd(&lds_u[seg >> 1], 1u << ((seg & 1) * 16));
        }
        __syncthreads();
        unsigned* out32 = reinterpret_cast<unsigned*>(histm16) + (size_t)blockIdx.x * 16384;
        for (int i = tid; i < 16384; i += 512) out32[i] = lds_u[i];
    } else {
        unsigned short (*A)[72] = reinterpret_cast<unsigned short(*)[72]>(lds_u);
        const int g0 = (blockIdx.x - SORTBLK2) * 128;
        for (int i = 0; i < 16; ++i) {
            int idx = i * 512 + tid;
            int node = idx >> 6, f = idx & 63;
            A[node][f] = f2b(X[(size_t)(g0 + node) * DNF + f]);
        }
        __syncthreads();
        const int wave = tid >> 6, lane = tid & 63;
        const int lr = lane & 15, lq = lane >> 4;
        const int arow = wave * 16 + lr;
        s16x8 a[2];
#pragma unroll
        for (int ks = 0; ks < 2; ++ks)
            a[ks] = *reinterpret_cast<const s16x8*>(&A[arow][ks * 32 + lq * 8]);
#pragma unroll
        for (int nt = 0; nt < 8; ++nt) {
            f32x4 accP = {0.f, 0.f, 0.f, 0.f};
#pragma unroll
            for (int ks = 0; ks < 2; ++ks) {
                s16x8 bp = *reinterpret_cast<const s16x8*>(&Pw[(((nt << 1) + ks) * 64 + lane) * 8]);
                accP = __builtin_amdgcn_mfma_f32_16x16x32_bf16(a[ks], bp, accP, 0, 0, 0);
            }
            int col = nt * 16 + lr;
#pragma unroll
            for (int j = 0; j < 4; ++j) {
                int row = g0 + wave * 16 + lq * 4 + j;
                Pp[(size_t)row * 128 + col] = f2b(accP[j]);
            }
        }
    }
}

// K2a: column-wise exclusive prefix over histm16[256][32768] in place; totals out.
__launch_bounds__(256)
__global__ void scan_cols(unsigned short* __restrict__ histm16, unsigned* __restrict__ totals) {
    const int col = blockIdx.x * 256 + threadIdx.x;
    unsigned run = 0;
    for (int b = 0; b < SORTBLK2; ++b) {
        unsigned v = histm16[(size_t)b * NSEG + col];
        histm16[(size_t)b * NSEG + col] = (unsigned short)run;
        run += v;
    }
    totals[col] = run;
}

// K2b: exclusive scan of 32768 segment totals -> segBase[0..32768].
__launch_bounds__(1024)
__global__ void scan_tot(const unsigned* __restrict__ totals, unsigned* __restrict__ segBase) {
    __shared__ unsigned part[1024];
    const int t = threadIdx.x;
    unsigned v[32]; unsigned s = 0;
#pragma unroll
    for (int i = 0; i < 32; ++i) { v[i] = totals[t * 32 + i]; s += v[i]; }
    part[t] = s;
    __syncthreads();
    for (int off = 1; off < 1024; off <<= 1) {
        unsigned x = (t >= off) ? part[t - off] : 0u;
        __syncthreads();
        part[t] += x;
        __syncthreads();
    }
    unsigned run = t ? part[t - 1] : 0u;
#pragma unroll
    for (int i = 0; i < 32; ++i) { segBase[t * 32 + i] = run; run += v[i]; }
    if (t == 1023) segBase[NSEG] = run;
}

// K3: deterministic segment-sorted scatter. pos = segBase[seg] + histm[blk][seg]
// + local (packed-u16 LDS cursor). Fire-and-forget stores, zero global atomics.
// payload = dst[0:12) | w13[12:25)
__launch_bounds__(512, 4)
__global__ void sort_scatter(const int* __restrict__ eb, const int* __restrict__ esrc,
                             const int* __restrict__ edst, const float* __restrict__ evals,
                             const unsigned short* __restrict__ histm16,
                             const unsigned* __restrict__ segBase,
                             unsigned* __restrict__ payslot) {
    __shared__ unsigned curP[16384];    // 64 KB packed u16 cursors
    const int tid = threadIdx.x, blk = blockIdx.x;
    for (int i = tid; i < 16384; i += 512) curP[i] = 0;
    __syncthreads();
    const unsigned short* hrow = histm16 + (size_t)blk * NSEG;
    const int e0 = blk * EPB2;
#pragma unroll
    for (int i = 0; i < EPB2 / 512; ++i) {
        int e = e0 + i * 512 + tid;
        int seg = eb[e] * NN + esrc[e];
        unsigned wq = (unsigned)fminf(evals[e] * 8192.0f + 0.5f, 8191.0f);
        unsigned pay = (unsigned)edst[e] | (wq << 12);
        unsigned sh = (unsigned)(seg & 1) * 16u;
        unsigned old = atomicAdd(&curP[seg >> 1], 1u << sh);
        unsigned l = (old >> sh) & 0xffffu;
        payslot[segBase[seg] + (unsigned)hrow[seg] + l] = pay;
    }
}

// Pass B: 16 nodes per block. Payload globally segment-sorted & dense -> stage
// the block's range into LDS (no sort, chunked for guaranteed correctness),
// reduce off LDS (short-latency chain), Q in-block via MFMA, fused node MLP.
__launch_bounds__(256, 8)
__global__ void bucket16_fused(const unsigned short* __restrict__ Pp,
                               const unsigned* __restrict__ payslot,
                               const unsigned* __restrict__ segBase,
                               const unsigned short* __restrict__ Qw,
                               const float* __restrict__ b1,
                               const unsigned short* __restrict__ Wm2p,
                               const float* __restrict__ b2m,
                               const float* __restrict__ X,
                               const unsigned short* __restrict__ Wu1p,
                               const float* __restrict__ bu1,
                               const unsigned short* __restrict__ Wu2p,
                               const float* __restrict__ bu2,
                               float* __restrict__ out) {
    __shared__ unsigned pays[PCHUNK];
    __shared__ unsigned short A1[16][136];
    __shared__ unsigned short Qs[16][136];
    __shared__ unsigned short S[16][136];
    __shared__ unsigned short Hs[16][136];
    __shared__ float SW[16], SC[16];
    const int tid = threadIdx.x, wv = tid >> 6, lane = tid & 63;
    // XCD-affine swizzle: blocks round-robin XCDs; give XCD x the buckets of batch x.
    const int bkt = (blockIdx.x & 7) * 256 + (blockIdx.x >> 3);
    const int node0 = bkt * SPB2;
    const int rowbase = (bkt >> 8) << 12;         // batch * NN
    const int lr = lane & 15, lq = lane >> 4;

    // stage node feats into A1[:, 0:64]
#pragma unroll
    for (int i = 0; i < 4; ++i) {
        int idx = i * 256 + tid;
        int row = idx >> 6, f = idx & 63;
        A1[row][f] = f2b(X[(size_t)(node0 + row) * DNF + f]);
    }
    __syncthreads();

    // Q in-block: Qs[16][128] = X_tile @ Wm1[:64] + b1 (bias folded)
    {
        s16x8 a[2];
#pragma unroll
        for (int ks = 0; ks < 2; ++ks)
            a[ks] = *reinterpret_cast<const s16x8*>(&A1[lr][ks * 32 + lq * 8]);
#pragma unroll
        for (int t = 0; t < 2; ++t) {
            int nt = wv * 2 + t;
            f32x4 acc = {0.f, 0.f, 0.f, 0.f};
#pragma unroll
            for (int ks = 0; ks < 2; ++ks) {
                s16x8 bq = *reinterpret_cast<const s16x8*>(&Qw[(((nt << 1) + ks) * 64 + lane) * 8]);
                acc = __builtin_amdgcn_mfma_f32_16x16x32_bf16(a[ks], bq, acc, 0, 0, 0);
            }
            int col = nt * 16 + lr;
            float bias = b1[col];
#pragma unroll
            for (int j = 0; j < 4; ++j)
                Qs[lq * 4 + j][col] = f2b(acc[j] + bias);
        }
    }
    __syncthreads();

    const unsigned* P32 = reinterpret_cast<const unsigned*>(Pp);
    const unsigned* PbS = P32 + (size_t)rowbase * 64;

    // per-wave segment state (persists across payload chunks)
    f32x2 q2[4], acc2[4];
    float wsum[4];
    unsigned s0g[4], s1g[4];
#pragma unroll
    for (int si = 0; si < 4; ++si) {
        const int lo = wv * 4 + si;
        const int seg = node0 + lo;
        s0g[si] = segBase[seg];
        s1g[si] = segBase[seg + 1];
        unsigned qv = *reinterpret_cast<const unsigned*>(&Qs[lo][2 * lane]);
        q2[si].x = uif(qv << 16); q2[si].y = uif(qv & 0xffff0000u);
        acc2[si].x = 0.f; acc2[si].y = 0.f;
        wsum[si] = 0.f;
    }

    const unsigned start = segBase[node0], endAll = segBase[node0 + 16];
    for (unsigned cbase = start; cbase < endAll; cbase += PCHUNK) {
        const unsigned n = min((unsigned)PCHUNK, endAll - cbase);
        __syncthreads();                               // pays reuse across chunks
        for (unsigned i = tid; i < n; i += 256)
            pays[i] = payslot[cbase + i];              // coalesced, already sorted
        __syncthreads();

#pragma unroll
        for (int si = 0; si < 4; ++si) {
            unsigned a = max(s0g[si], cbase);
            unsigned b = min(s1g[si], cbase + n);
            for (unsigned bse = a; bse < b; bse += 8) {
                unsigned pv[8]; float wf[8];
#pragma unroll
                for (int k = 0; k < 8; ++k) {
                    unsigned idx = bse + (unsigned)k;
                    unsigned cu = (idx < b) ? pays[idx - cbase] : 0u;  // wave-uniform LDS
                    int ci = __builtin_amdgcn_readfirstlane((int)cu);
                    wf[k] = (float)(unsigned)((ci >> 12) & 8191);      // integer-valued
                    int row = ci & 0xfff;
                    pv[k] = PbS[(size_t)row * 64 + lane];              // SADDR-form load
                }
#pragma unroll
                for (int k = 0; k < 8; ++k) {
                    f32x2 p2 = { uif(pv[k] << 16), uif(pv[k] & 0xffff0000u) };
                    f32x2 h2 = q2[si] + p2;
                    h2 = __builtin_elementwise_max(h2, (f32x2){0.f, 0.f});
                    acc2[si] += wf[k] * h2;
                    wsum[si] += wf[k];                                 // wave-uniform
                }
            }
        }
    }

#pragma unroll
    for (int si = 0; si < 4; ++si) {
        const int lo = wv * 4 + si;
        unsigned sp = (unsigned)f2b(acc2[si].x) | ((unsigned)f2b(acc2[si].y) << 16);
        *reinterpret_cast<unsigned*>(&S[lo][2 * lane]) = sp;
        if (lane == 0) {
            SW[lo] = wsum[si];
            SC[lo] = (1.0f / 8192.0f) / (float)max(s1g[si] - s0g[si], 1u);
        }
    }
    __syncthreads();

    // gathered = (S @ Wm2 + sumw*b2) * SC -> A1[:, 64:128] (bf16)
    {
        s16x8 a[4];
#pragma unroll
        for (int ks = 0; ks < 4; ++ks)
            a[ks] = *reinterpret_cast<const s16x8*>(&S[lr][ks * 32 + lq * 8]);
        f32x4 acc = {0.f, 0.f, 0.f, 0.f};
#pragma unroll
        for (int ks = 0; ks < 4; ++ks) {
            s16x8 bf = *reinterpret_cast<const s16x8*>(&Wm2p[(((wv << 2) + ks) * 64 + lane) * 8]);
            acc = __builtin_amdgcn_mfma_f32_16x16x32_bf16(a[ks], bf, acc, 0, 0, 0);
        }
        float bb = b2m[wv * 16 + lr];
#pragma unroll
        for (int j = 0; j < 4; ++j) {
            int r = lq * 4 + j;
            float g = (acc[j] + SW[r] * bb) * SC[r];
            A1[r][64 + wv * 16 + lr] = f2b(g);
        }
    }
    __syncthreads();

    // node MLP layer 1: relu([X|gathered] @ Wu1 + bu1) -> Hs
    {
        s16x8 a1[4];
#pragma unroll
        for (int ks = 0; ks < 4; ++ks)
            a1[ks] = *reinterpret_cast<const s16x8*>(&A1[lr][ks * 32 + lq * 8]);
#pragma unroll
        for (int t = 0; t < 2; ++t) {
            int nt = wv * 2 + t;
            f32x4 acc = {0.f, 0.f, 0.f, 0.f};
#pragma unroll
            for (int ks = 0; ks < 4; ++ks) {
                s16x8 bf = *reinterpret_cast<const s16x8*>(&Wu1p[(((nt << 2) + ks) * 64 + lane) * 8]);
                acc = __builtin_amdgcn_mfma_f32_16x16x32_bf16(a1[ks], bf, acc, 0, 0, 0);
            }
            float bias = bu1[nt * 16 + lr];
#pragma unroll
            for (int j = 0; j < 4; ++j) {
                float hh = fmaxf(acc[j] + bias, 0.f);
                Hs[lq * 4 + j][nt * 16 + lr] = f2b(hh);
            }
        }
    }
    __syncthreads();

    // layer 2: Hs @ Wu2 + bu2 -> out
    {
        s16x8 a2[4];
#pragma unroll
        for (int ks = 0; ks < 4; ++ks)
            a2[ks] = *reinterpret_cast<const s16x8*>(&Hs[lr][ks * 32 + lq * 8]);
        f32x4 acc = {0.f, 0.f, 0.f, 0.f};
#pragma unroll
        for (int ks = 0; ks < 4; ++ks) {
            s16x8 bf = *reinterpret_cast<const s16x8*>(&Wu2p[(((wv << 2) + ks) * 64 + lane) * 8]);
            acc = __builtin_amdgcn_mfma_f32_16x16x32_bf16(a2[ks], bf, acc, 0, 0, 0);
        }
        float bias = bu2[wv * 16 + lr];
#pragma unroll
        for (int j = 0; j < 4; ++j)
            out[(size_t)(node0 + lq * 4 + j) * FF + wv * 16 + lr] = acc[j] + bias;
    }
}

// ---------------- legacy fallback (small ws) ----------------

template<int SCALE>
__launch_bounds__(256, 4)
__global__ void node_kernel(const float* __restrict__ node_feats,
                            const float* __restrict__ sums, const float* __restrict__ counts,
                            const unsigned short* __restrict__ W1p, const float* __restrict__ b1,
                            const unsigned short* __restrict__ W2p, const float* __restrict__ b2,
                            float* __restrict__ out) {
    __shared__ unsigned short A1[64][136];
    __shared__ unsigned short Hs[64][136];
    const int tid = threadIdx.x;
    const int g0 = blockIdx.x * 64;
    for (int i = 0; i < 16; ++i) {
        int idx = i * 256 + tid;
        int node = idx >> 6;
        int p = idx & 63;
        int g = g0 + node;
        float2 v;
        if (p < 32) {
            v = *reinterpret_cast<const float2*>(node_feats + (size_t)g * DNF + 2 * p);
        } else {
            float2 s = *reinterpret_cast<const float2*>(sums + (size_t)g * DM + 2 * p - 64);
            if (SCALE) {
                float scale = 1.0f / fmaxf(counts[g], 1.0f);
                s.x *= scale; s.y *= scale;
            }
            v = s;
        }
        unsigned packed = (unsigned)f2b(v.x) | ((unsigned)f2b(v.y) << 16);
        *reinterpret_cast<unsigned*>(&A1[node][2 * p]) = packed;
    }
    __syncthreads();
    const int wave = tid >> 6, lane = tid & 63;
    const int lr = lane & 15, lq = lane >> 4;
    const int arow = wave * 16 + lr;
    s16x8 a[4];
#pragma unroll
    for (int ks = 0; ks < 4; ++ks)
        a[ks] = *reinterpret_cast<const s16x8*>(&A1[arow][ks * 32 + lq * 8]);
#pragma unroll
    for (int nt = 0; nt < 8; ++nt) {
        f32x4 acc = {0.f, 0.f, 0.f, 0.f};
#pragma unroll
        for (int ks = 0; ks < 4; ++ks) {
            s16x8 bf = *reinterpret_cast<const s16x8*>(&W1p[(((nt << 2) + ks) * 64 + lane) * 8]);
            acc = __builtin_amdgcn_mfma_f32_16x16x32_bf16(a[ks], bf, acc, 0, 0, 0);
        }
        float bias = b1[nt * 16 + lr];
#pragma unroll
        for (int j = 0; j < 4; ++j) {
            float h = acc[j] + bias;
            h = h > 0.f ? h : 0.f;
            Hs[wave * 16 + lq * 4 + j][nt * 16 + lr] = f2b(h);
        }
    }
    s16x8 a2[4];
#pragma unroll
    for (int ks = 0; ks < 4; ++ks)
        a2[ks] = *reinterpret_cast<const s16x8*>(&Hs[arow][ks * 32 + lq * 8]);
#pragma unroll
    for (int nt = 0; nt < 4; ++nt) {
        f32x4 acc = {0.f, 0.f, 0.f, 0.f};
#pragma unroll
        for (int ks = 0; ks < 4; ++ks) {
            s16x8 bf = *reinterpret_cast<const s16x8*>(&W2p[(((nt << 2) + ks) * 64 + lane) * 8]);
            acc = __builtin_amdgcn_mfma_f32_16x16x32_bf16(a2[ks], bf, acc, 0, 0, 0);
        }
        float bias = b2[nt * 16 + lr];
#pragma unroll
        for (int j = 0; j < 4; ++j) {
            int g = g0 + wave * 16 + lq * 4 + j;
            out[(size_t)g * FF + nt * 16 + lr] = acc[j] + bias;
        }
    }
}

__launch_bounds__(256, 4)
__global__ void edge_kernel(const float* __restrict__ node_feats,
                            const int* __restrict__ eb, const int* __restrict__ esrc,
                            const int* __restrict__ edst, const float* __restrict__ evals,
                            const unsigned short* __restrict__ W1p, const float* __restrict__ b1,
                            const unsigned short* __restrict__ W2p, const float* __restrict__ b2,
                            float* __restrict__ sums, float* __restrict__ counts) {
    __shared__ unsigned short A1[64][136];
    __shared__ unsigned short Hs[64][136];
    const int tid = threadIdx.x;
    const int e0 = blockIdx.x * 64;
    if (tid < 64) {
        int e = e0 + tid;
        atomicAdd(&counts[eb[e] * NN + esrc[e]], 1.0f);
    }
    for (int i = 0; i < 16; ++i) {
        int idx = i * 256 + tid;
        int edge = idx >> 6;
        int p = idx & 63;
        int e = e0 + edge;
        int b = eb[e];
        const float* row;
        if (p < 32) row = node_feats + ((size_t)b * NN + esrc[e]) * DNF;
        else        row = node_feats + ((size_t)b * NN + edst[e]) * DNF - 64;
        float2 v = *reinterpret_cast<const float2*>(row + 2 * p);
        unsigned packed = (unsigned)f2b(v.x) | ((unsigned)f2b(v.y) << 16);
        *reinterpret_cast<unsigned*>(&A1[edge][2 * p]) = packed;
    }
    __syncthreads();
    const int wave = tid >> 6, lane = tid & 63;
    const int lr = lane & 15, lq = lane >> 4;
    const int arow = wave * 16 + lr;
    s16x8 a[4];
#pragma unroll
    for (int ks = 0; ks < 4; ++ks)
        a[ks] = *reinterpret_cast<const s16x8*>(&A1[arow][ks * 32 + lq * 8]);
#pragma unroll
    for (int nt = 0; nt < 8; ++nt) {
        f32x4 acc = {0.f, 0.f, 0.f, 0.f};
#pragma unroll
        for (int ks = 0; ks < 4; ++ks) {
            s16x8 bf = *reinterpret_cast<const s16x8*>(&W1p[(((nt << 2) + ks) * 64 + lane) * 8]);
            acc = __builtin_amdgcn_mfma_f32_16x16x32_bf16(a[ks], bf, acc, 0, 0, 0);
        }
        float bias = b1[nt * 16 + lr];
#pragma unroll
        for (int j = 0; j < 4; ++j) {
            float h = acc[j] + bias;
            h = h > 0.f ? h : 0.f;
            Hs[wave * 16 + lq * 4 + j][nt * 16 + lr] = f2b(h);
        }
    }
    s16x8 a2[4];
#pragma unroll
    for (int ks = 0; ks < 4; ++ks)
        a2[ks] = *reinterpret_cast<const s16x8*>(&Hs[arow][ks * 32 + lq * 8]);
    float ev[4]; int seg4[4];
#pragma unroll
    for (int j = 0; j < 4; ++j) {
        int r = e0 + wave * 16 + lq * 4 + j;
        ev[j] = evals[r];
        seg4[j] = eb[r] * NN + esrc[r];
    }
#pragma unroll
    for (int nt = 0; nt < 4; ++nt) {
        f32x4 acc = {0.f, 0.f, 0.f, 0.f};
#pragma unroll
        for (int ks = 0; ks < 4; ++ks) {
            s16x8 bf = *reinterpret_cast<const s16x8*>(&W2p[(((nt << 2) + ks) * 64 + lane) * 8]);
            acc = __builtin_amdgcn_mfma_f32_16x16x32_bf16(a2[ks], bf, acc, 0, 0, 0);
        }
        float bias = b2[nt * 16 + lr];
#pragma unroll
        for (int j = 0; j < 4; ++j) {
            float m = (acc[j] + bias) * ev[j];
            atomicAdd(&sums[(size_t)seg4[j] * DM + nt * 16 + lr], m);
        }
    }
}

extern "C" void kernel_launch(void* const* d_in, const int* in_sizes, int n_in,
                              void* d_out, int out_size, void* d_ws, size_t ws_size,
                              hipStream_t stream) {
    const float* node_feats = (const float*)d_in[0];
    const int*   eb    = (const int*)d_in[1];
    const int*   esrc  = (const int*)d_in[2];
    const int*   edst  = (const int*)d_in[3];
    const float* evals = (const float*)d_in[4];
    const float* Wm1 = (const float*)d_in[5];
    const float* bm1 = (const float*)d_in[6];
    const float* Wm2 = (const float*)d_in[7];
    const float* bm2 = (const float*)d_in[8];
    const float* Wu1 = (const float*)d_in[9];
    const float* bu1 = (const float*)d_in[10];
    const float* Wu2 = (const float*)d_in[11];
    const float* bu2 = (const float*)d_in[12];
    float* out = (float*)d_out;
    char* ws = (char*)d_ws;

    const size_t NEED = 29720704;   // proven available
    if (ws_size >= NEED) {
        unsigned short* Pp      = (unsigned short*)(ws);              // 8 MB
        unsigned*       payslot = (unsigned*)(ws + 8388608);          // 4 MB
        unsigned short* histm16 = (unsigned short*)(ws + 12582912);   // 256*32768*2 = 16 MB
        unsigned*       segBase = (unsigned*)(ws + 29360128);         // 32769*4 (pad 131200)
        unsigned*       totals  = (unsigned*)(ws + 29491328);         // 128 KB
        unsigned short* Qw      = (unsigned short*)(ws + 29622400);   // 16 KB
        unsigned short* Pw      = (unsigned short*)(ws + 29638784);   // 16 KB
        unsigned short* Wu1p    = (unsigned short*)(ws + 29655168);   // 32 KB
        unsigned short* Wu2p    = (unsigned short*)(ws + 29687936);   // 16 KB
        unsigned short* Wm2p    = (unsigned short*)(ws + 29704320);   // 16 KB

        pack_all<<<192, 256, 0, stream>>>(Wm1, Wm2, Wu1, Wu2, Qw, Pw, Wm2p, Wu1p, Wu2p);
        hist_p<<<2 * SORTBLK2, 512, 0, stream>>>(eb, esrc, histm16, node_feats, Pw, Pp);
        scan_cols<<<NSEG / 256, 256, 0, stream>>>(histm16, totals);
        scan_tot<<<1, 1024, 0, stream>>>(totals, segBase);
        sort_scatter<<<SORTBLK2, 512, 0, stream>>>(eb, esrc, edst, evals,
                                                   histm16, segBase, payslot);
        bucket16_fused<<<NSEG / SPB2, 256, 0, stream>>>(Pp, payslot, segBase,
                                                        Qw, bm1, Wm2p, bm2, node_feats,
                                                        Wu1p, bu1, Wu2p, bu2, out);
    } else {
        float* counts          = (float*)ws;
        unsigned short* W1p    = (unsigned short*)(ws + 131072);
        unsigned short* W2p    = (unsigned short*)(ws + 163840);
        unsigned short* Wu1p   = (unsigned short*)(ws + 180224);
        unsigned short* Wu2p   = (unsigned short*)(ws + 212992);
        hipMemsetAsync(d_out, 0, (size_t)out_size * sizeof(float), stream);
        hipMemsetAsync(counts, 0, 32768 * sizeof(float), stream);
        pack_weights<<<64, 256, 0, stream>>>(Wm1, W1p, 128, 128);
        pack_weights<<<32, 256, 0, stream>>>(Wm2, W2p, 128, 64);
        pack_weights<<<64, 256, 0, stream>>>(Wu1, Wu1p, 128, 128);
        pack_weights<<<32, 256, 0, stream>>>(Wu2, Wu2p, 128, 64);
        edge_kernel<<<NEDGE / 64, 256, 0, stream>>>(node_feats, eb, esrc, edst, evals,
                                                    W1p, bm1, W2p, bm2, out, counts);
        node_kernel<1><<<(NB * NN) / 64, 256, 0, stream>>>(node_feats, out, counts,
                                                           Wu1p, bu1, Wu2p, bu2, out);
    }
}